// Round 17
// baseline (154.307 us; speedup 1.0000x reference)
//
#include <hip/hip_runtime.h>
#include <cstdint>

#define DEV static __device__ __forceinline__

typedef __attribute__((__ext_vector_type__(8))) __bf16 bf16x8;
typedef __attribute__((__ext_vector_type__(4))) float f32x4;

static constexpr int Bc = 16, Sc = 2048, Dc = 1024;

DEV unsigned short f2bf(float x) {
  unsigned int u = __float_as_uint(x);
  unsigned int r = (u + 0x7fffu + ((u >> 16) & 1u)) >> 16;
  return (unsigned short)r;
}
DEV unsigned int pack2(float a, float b) {
  return (unsigned int)f2bf(a) | ((unsigned int)f2bf(b) << 16);
}
DEV float tanh_fast(float x) {
  return 1.f - 2.f / (__expf(2.f * x) + 1.f);
}
DEV void gload16(const void* g, void* l) {
  __builtin_amdgcn_global_load_lds(
      (const __attribute__((address_space(1))) unsigned int*)g,
      (__attribute__((address_space(3))) unsigned int*)l, 16, 0, 0);
}

// ---- kernel 1: FUSED prep (one launch, independent work co-scheduled):
//   blocks [0,2048):    enc fp32->bf16 (length-skipped) -- the long pole
//   blocks [2048,3072): hidproj e = bx-2048 (+ worklist in block 2048)
//   blocks [3072,3584): We fp32->bf16
__global__ __launch_bounds__(256) void k_prep(const float* __restrict__ enc,
                                              const float* __restrict__ hidden,
                                              const float* __restrict__ W,
                                              const float* __restrict__ bias,
                                              const int* __restrict__ lengths,
                                              unsigned short* __restrict__ ebf,
                                              unsigned short* __restrict__ webf,
                                              float* __restrict__ hp,
                                              int* __restrict__ wl) {
  int bx = blockIdx.x;
  int t = threadIdx.x;
  if (bx < 2048) {
    int team = t >> 7, lane = t & 127;
    int r0 = bx * 16;
    int b = r0 >> 11;
    int len = lengths[b];
    for (int rr = team; rr < 16; rr += 2) {
      int s = (r0 + rr) & 2047;
      if (s >= len) continue;
      const float* src = enc + (size_t)(r0 + rr) * Dc + lane * 8;
      unsigned short* dst = ebf + (size_t)(r0 + rr) * Dc + lane * 8;
      float4 f0 = *(const float4*)src;
      float4 f1 = *(const float4*)(src + 4);
      uint4 o;
      o.x = pack2(f0.x, f0.y);
      o.y = pack2(f0.z, f0.w);
      o.z = pack2(f1.x, f1.y);
      o.w = pack2(f1.z, f1.w);
      *(uint4*)dst = o;
    }
  } else if (bx < 3072) {
    int e = bx - 2048;
    if (e == 0) {
      int sblk = t >> 4, b = t & 15;  // t = sblk*16 + b
      int active = (sblk * 128 < lengths[b]) ? 1 : 0;
      unsigned long long mask = __ballot(active);
      int lane = t & 63, wid = t >> 6;
      int prefix = __popcll(mask & ((1ull << lane) - 1ull));
      __shared__ int woff[4];
      if (lane == 0) woff[wid] = __popcll(mask);
      __syncthreads();
      int base = 0;
      for (int i = 0; i < wid; i++) base += woff[i];
      if (active) wl[1 + base + prefix] = (b << 8) | sblk;
      if (t == 0) wl[0] = woff[0] + woff[1] + woff[2] + woff[3];
    }
    __shared__ float wrow[Dc];
    for (int i = t; i < Dc; i += 256) wrow[i] = W[(size_t)e * 2048 + i];
    __syncthreads();
    int w = t >> 6, lane = t & 63;
    float bv = bias[e];
    for (int bi = w; bi < Bc; bi += 4) {
      float s = 0.f;
      const float* hrow = hidden + (size_t)bi * Dc;
      for (int d = lane; d < Dc; d += 64) s += hrow[d] * wrow[d];
      for (int m = 1; m < 64; m <<= 1) s += __shfl_xor(s, m);
      if (lane == 0) hp[(size_t)bi * Dc + e] = s + bv;
    }
  } else {
    int i = ((bx - 3072) * 256 + t) * 8;
    int e = i >> 10, d = i & 1023;
    const float* p = W + (size_t)e * 2048 + 1024 + d;
    float4 f0 = *(const float4*)p;
    float4 f1 = *(const float4*)(p + 4);
    uint4 o;
    o.x = pack2(f0.x, f0.y);
    o.y = pack2(f0.z, f0.w);
    o.z = pack2(f1.x, f1.y);
    o.w = pack2(f1.z, f1.w);
    *(uint4*)(webf + i) = o;
  }
}

// ---- kernel 2: scores GEMM (bf16 MFMA) + tanh + v-dot, per-e-tile partials.
// EXACT round-12 body (best measured: 95.3 total): counted vmcnt(4) across
// raw barriers, T2 both-sides LDS swizzle, T5 setprio, worklist mapping
// g=bx&255 / et=bx>>8 (XCD affinity: all 8 e-tiles of a panel share bx%8).
__global__ __launch_bounds__(256) void k_scores(const unsigned short* __restrict__ Ae,
                                                const unsigned short* __restrict__ We,
                                                const float* __restrict__ hp,
                                                const float* __restrict__ v,
                                                const int* __restrict__ wl,
                                                float* __restrict__ pscores) {
  int g = blockIdx.x & 255;
  int et = blockIdx.x >> 8;
  if (g >= wl[0]) return;
  int pk = wl[1 + g];
  int b = pk >> 8, sblk = pk & 255;
  int s0 = sblk * 128;
  int m0 = b * Sc + s0;
  int e0 = et * 128;

  __shared__ unsigned short As0[128 * 32];
  __shared__ unsigned short As1[128 * 32];
  __shared__ unsigned short Bs0[128 * 32];
  __shared__ unsigned short Bs1[128 * 32];
  __shared__ float hp_s[128], v_s[128], sc_s[128];

  int t = threadIdx.x;
  int w = t >> 6, lane = t & 63;
  if (t < 128) {
    hp_s[t] = hp[(size_t)b * Dc + e0 + t];
    v_s[t] = v[e0 + t];
    sc_s[t] = 0.f;
  }
  // Drain prologue loads (and their LDS writes) so vmcnt counting is exact.
  asm volatile("s_waitcnt vmcnt(0) lgkmcnt(0)" ::: "memory");

  f32x4 acc[4][4] = {};
  int wr = w >> 1, wc = w & 1;

  // Staging source pre-swizzle: octet o=t>>3 covers row-pair o (rows 2o,2o+1);
  // slot q=t&7 holds global slot g8=q^(o&7): row 2o+(g8>>2), chunk g8&3.
  {
    int o = t >> 3, q = t & 7;
    int g8 = q ^ (o & 7);
    int srow = 2 * o + (g8 >> 2);
    int scol = (g8 & 3) * 8;
    Ae += (size_t)(m0 + srow) * Dc + scol;
    We += (size_t)(e0 + srow) * Dc + scol;
  }
  const unsigned short* ga0 = Ae;
  const unsigned short* gb0 = We;

  // Read-side swizzle (per-lane constants).
  int posw = (((lane & 1) << 2) + (lane >> 4)) ^ (((lane & 15) >> 1) & 7);
  int aoff = (wr * 32 + ((lane & 15) >> 1)) * 64 + posw * 8;
  int boff = (wc * 32 + ((lane & 15) >> 1)) * 64 + posw * 8;

  auto stage = [&](int k0, unsigned short* A, unsigned short* B) {
    gload16(ga0 + k0, A + w * 512);
    gload16(ga0 + k0 + 64 * Dc, A + 2048 + w * 512);
    gload16(gb0 + k0, B + w * 512);
    gload16(gb0 + k0 + 64 * Dc, B + 2048 + w * 512);
  };
  auto compute = [&](const unsigned short* A, const unsigned short* B) {
    bf16x8 af[4], bfr[4];
#pragma unroll
    for (int m = 0; m < 4; m++)
      af[m] = __builtin_bit_cast(bf16x8, *(const uint4*)(A + aoff + m * 512));
#pragma unroll
    for (int n = 0; n < 4; n++)
      bfr[n] = __builtin_bit_cast(bf16x8, *(const uint4*)(B + boff + n * 512));
    __builtin_amdgcn_s_setprio(1);
#pragma unroll
    for (int m = 0; m < 4; m++)
#pragma unroll
      for (int n = 0; n < 4; n++)
        acc[m][n] = __builtin_amdgcn_mfma_f32_16x16x32_bf16(af[m], bfr[n], acc[m][n], 0, 0, 0);
    __builtin_amdgcn_s_setprio(0);
  };

  stage(0, As0, Bs0);  // 4 outstanding

#pragma unroll 1
  for (int i2 = 0; i2 < 15; ++i2) {
    stage((2 * i2 + 1) * 32, As1, Bs1);                // 8 outstanding
    asm volatile("s_waitcnt vmcnt(4)" ::: "memory");   // even tile landed
    __builtin_amdgcn_sched_barrier(0);
    __builtin_amdgcn_s_barrier();
    __builtin_amdgcn_sched_barrier(0);
    compute(As0, Bs0);
    __builtin_amdgcn_sched_barrier(0);
    __builtin_amdgcn_s_barrier();
    stage((2 * i2 + 2) * 32, As0, Bs0);
    asm volatile("s_waitcnt vmcnt(4)" ::: "memory");
    __builtin_amdgcn_sched_barrier(0);
    __builtin_amdgcn_s_barrier();
    __builtin_amdgcn_sched_barrier(0);
    compute(As1, Bs1);
    __builtin_amdgcn_sched_barrier(0);
    __builtin_amdgcn_s_barrier();
  }
  // tail: tile 30 in As0/Bs0; stage 31, compute both.
  stage(31 * 32, As1, Bs1);
  asm volatile("s_waitcnt vmcnt(4)" ::: "memory");
  __builtin_amdgcn_sched_barrier(0);
  __builtin_amdgcn_s_barrier();
  __builtin_amdgcn_sched_barrier(0);
  compute(As0, Bs0);
  __builtin_amdgcn_sched_barrier(0);
  __builtin_amdgcn_s_barrier();
  asm volatile("s_waitcnt vmcnt(0)" ::: "memory");
  __builtin_amdgcn_sched_barrier(0);
  __builtin_amdgcn_s_barrier();
  __builtin_amdgcn_sched_barrier(0);
  compute(As1, Bs1);

  // epilogue: rowsum_e( v[e] * tanh(acc + hp[e]) )
  for (int m = 0; m < 4; m++) {
    float rs0 = 0.f, rs1 = 0.f, rs2 = 0.f, rs3 = 0.f;
    for (int n = 0; n < 4; n++) {
      int ec = wc * 64 + n * 16 + (lane & 15);
      float hpv = hp_s[ec], vv = v_s[ec];
      f32x4 a = acc[m][n];
      rs0 += vv * tanh_fast(a[0] + hpv);
      rs1 += vv * tanh_fast(a[1] + hpv);
      rs2 += vv * tanh_fast(a[2] + hpv);
      rs3 += vv * tanh_fast(a[3] + hpv);
    }
    for (int mask = 1; mask < 16; mask <<= 1) {
      rs0 += __shfl_xor(rs0, mask);
      rs1 += __shfl_xor(rs1, mask);
      rs2 += __shfl_xor(rs2, mask);
      rs3 += __shfl_xor(rs3, mask);
    }
    if ((lane & 15) == 0) {  // exactly 2 adders per row (wc=0,1): deterministic
      int rbase = wr * 64 + m * 16 + (lane >> 4) * 4;
      atomicAdd(&sc_s[rbase + 0], rs0);
      atomicAdd(&sc_s[rbase + 1], rs1);
      atomicAdd(&sc_s[rbase + 2], rs2);
      atomicAdd(&sc_s[rbase + 3], rs3);
    }
  }
  __syncthreads();
  if (t < 128) pscores[((size_t)et * Bc + b) * Sc + s0 + t] = sc_s[t];
}

// ---- kernel 3: masked softmax over S per batch; sums 8 e-tile partials
__global__ __launch_bounds__(256) void k_softmax(const float* __restrict__ pscores,
                                                 const int* __restrict__ lengths,
                                                 float* __restrict__ attn) {
  int b = blockIdx.x, t = threadIdx.x;
  int len = lengths[b];
  float vals[8];
  float mx = -INFINITY;
  for (int i = 0; i < 8; i++) {
    int s = t + i * 256;
    float sc = 0.f;
    for (int p = 0; p < 8; p++) sc += pscores[((size_t)p * Bc + b) * Sc + s];
    sc = (s < len) ? sc : -INFINITY;
    vals[i] = sc;
    mx = fmaxf(mx, sc);
  }
  for (int m = 1; m < 64; m <<= 1) mx = fmaxf(mx, __shfl_xor(mx, m));
  __shared__ float rmax[4], rsum[4];
  int w = t >> 6, lane = t & 63;
  if (lane == 0) rmax[w] = mx;
  __syncthreads();
  mx = fmaxf(fmaxf(rmax[0], rmax[1]), fmaxf(rmax[2], rmax[3]));
  float sm = 0.f;
  for (int i = 0; i < 8; i++) {
    vals[i] = __expf(vals[i] - mx);
    sm += vals[i];
  }
  for (int m = 1; m < 64; m <<= 1) sm += __shfl_xor(sm, m);
  if (lane == 0) rsum[w] = sm;
  __syncthreads();
  sm = rsum[0] + rsum[1] + rsum[2] + rsum[3];
  float inv = 1.f / sm;
  for (int i = 0; i < 8; i++) attn[(size_t)b * Sc + t + i * 256] = vals[i] * inv;
}

// ---- kernel 4: context DIRECT: block (b, 64-d-chunk) sums its full s-range
// in fixed order and writes out[b][d] -- no pctx round-trip, no reduce pass.
// grid = 16 b * 16 chunks = 256 blocks; 4 s-groups of 64 lanes per block.
__global__ __launch_bounds__(256) void k_ctx(const unsigned short* __restrict__ ebf,
                                             const float* __restrict__ attn,
                                             const int* __restrict__ lengths,
                                             float* __restrict__ out) {
  int b = blockIdx.x >> 4, ch = blockIdx.x & 15;
  int t = threadIdx.x;
  int q = t >> 6, lane = t & 63;
  int d = ch * 64 + lane;
  int len = lengths[b];
  int len4 = (len + 3) >> 2;
  int sbeg = q * len4;
  int send = min(sbeg + len4, len);
  float acc0 = 0.f, acc1 = 0.f;
  const unsigned short* ebase = ebf + (size_t)b * Sc * Dc + d;
  const float* abase = attn + (size_t)b * Sc;
  int s = sbeg;
  for (; s + 1 < send; s += 2) {
    float w0 = abase[s], w1 = abase[s + 1];
    float e0 = __uint_as_float((unsigned int)ebase[(size_t)s * Dc] << 16);
    float e1 = __uint_as_float((unsigned int)ebase[(size_t)(s + 1) * Dc] << 16);
    acc0 += w0 * e0;
    acc1 += w1 * e1;
  }
  if (s < send)
    acc0 += abase[s] * __uint_as_float((unsigned int)ebase[(size_t)s * Dc] << 16);
  __shared__ float part[4][64];
  part[q][lane] = acc0 + acc1;
  __syncthreads();
  if (t < 64)  // fixed summation order -> deterministic
    out[(size_t)b * Dc + ch * 64 + t] =
        part[0][t] + part[1][t] + part[2][t] + part[3][t];
}

extern "C" void kernel_launch(void* const* d_in, const int* in_sizes, int n_in,
                              void* d_out, int out_size, void* d_ws, size_t ws_size,
                              hipStream_t stream) {
  const float* enc = (const float*)d_in[0];
  const float* hidden = (const float*)d_in[1];
  const int* lengths = (const int*)d_in[2];
  const float* W = (const float*)d_in[3];
  const float* bias = (const float*)d_in[4];
  const float* v = (const float*)d_in[5];
  float* out = (float*)d_out;

  char* ws = (char*)d_ws;
  unsigned short* ebf = (unsigned short*)ws;                // 64 MB
  unsigned short* webf = (unsigned short*)(ws + 67108864);  // 2 MB
  float* hp = (float*)(ws + 69206016);                      // 64 KB
  float* pscores = (float*)(ws + 69271552);                 // 1 MB
  float* attn = (float*)(ws + 70320128);                    // 128 KB
  int* wl = (int*)(ws + 70451200);                          // worklist

  hipLaunchKernelGGL(k_prep, dim3(3584), dim3(256), 0, stream, enc, hidden, W, bias,
                     lengths, ebf, webf, hp, wl);
  hipLaunchKernelGGL(k_scores, dim3(2048), dim3(256), 0, stream, ebf, webf, hp, v,
                     wl, pscores);
  hipLaunchKernelGGL(k_softmax, dim3(16), dim3(256), 0, stream, pscores, lengths, attn);
  hipLaunchKernelGGL(k_ctx, dim3(256), dim3(256), 0, stream, ebf, attn, lengths, out);
}

// Round 18
// 95.258 us; speedup vs baseline: 1.6199x; 1.6199x over previous
//
#include <hip/hip_runtime.h>
#include <cstdint>

#define DEV static __device__ __forceinline__

typedef __attribute__((__ext_vector_type__(8))) __bf16 bf16x8;
typedef __attribute__((__ext_vector_type__(4))) float f32x4;

static constexpr int Bc = 16, Sc = 2048, Dc = 1024;

DEV unsigned short f2bf(float x) {
  unsigned int u = __float_as_uint(x);
  unsigned int r = (u + 0x7fffu + ((u >> 16) & 1u)) >> 16;
  return (unsigned short)r;
}
DEV unsigned int pack2(float a, float b) {
  return (unsigned int)f2bf(a) | ((unsigned int)f2bf(b) << 16);
}
DEV float tanh_fast(float x) {
  return 1.f - 2.f / (__expf(2.f * x) + 1.f);
}
DEV void gload16(const void* g, void* l) {
  __builtin_amdgcn_global_load_lds(
      (const __attribute__((address_space(1))) unsigned int*)g,
      (__attribute__((address_space(3))) unsigned int*)l, 16, 0, 0);
}

// ---- kernel 1: FUSED prep (one launch, independent work co-scheduled):
//   blocks [0,2048):    enc fp32->bf16 (length-skipped) -- the long pole
//   blocks [2048,3072): hidproj e = bx-2048 (+ worklist in block 2048)
//   blocks [3072,3584): We fp32->bf16
__global__ __launch_bounds__(256) void k_prep(const float* __restrict__ enc,
                                              const float* __restrict__ hidden,
                                              const float* __restrict__ W,
                                              const float* __restrict__ bias,
                                              const int* __restrict__ lengths,
                                              unsigned short* __restrict__ ebf,
                                              unsigned short* __restrict__ webf,
                                              float* __restrict__ hp,
                                              int* __restrict__ wl) {
  int bx = blockIdx.x;
  int t = threadIdx.x;
  if (bx < 2048) {
    int team = t >> 7, lane = t & 127;
    int r0 = bx * 16;
    int b = r0 >> 11;
    int len = lengths[b];
    for (int rr = team; rr < 16; rr += 2) {
      int s = (r0 + rr) & 2047;
      if (s >= len) continue;
      const float* src = enc + (size_t)(r0 + rr) * Dc + lane * 8;
      unsigned short* dst = ebf + (size_t)(r0 + rr) * Dc + lane * 8;
      float4 f0 = *(const float4*)src;
      float4 f1 = *(const float4*)(src + 4);
      uint4 o;
      o.x = pack2(f0.x, f0.y);
      o.y = pack2(f0.z, f0.w);
      o.z = pack2(f1.x, f1.y);
      o.w = pack2(f1.z, f1.w);
      *(uint4*)dst = o;
    }
  } else if (bx < 3072) {
    int e = bx - 2048;
    if (e == 0) {
      int sblk = t >> 4, b = t & 15;  // t = sblk*16 + b
      int active = (sblk * 128 < lengths[b]) ? 1 : 0;
      unsigned long long mask = __ballot(active);
      int lane = t & 63, wid = t >> 6;
      int prefix = __popcll(mask & ((1ull << lane) - 1ull));
      __shared__ int woff[4];
      if (lane == 0) woff[wid] = __popcll(mask);
      __syncthreads();
      int base = 0;
      for (int i = 0; i < wid; i++) base += woff[i];
      if (active) wl[1 + base + prefix] = (b << 8) | sblk;
      if (t == 0) wl[0] = woff[0] + woff[1] + woff[2] + woff[3];
    }
    __shared__ float wrow[Dc];
    for (int i = t; i < Dc; i += 256) wrow[i] = W[(size_t)e * 2048 + i];
    __syncthreads();
    int w = t >> 6, lane = t & 63;
    float bv = bias[e];
    for (int bi = w; bi < Bc; bi += 4) {
      float s = 0.f;
      const float* hrow = hidden + (size_t)bi * Dc;
      for (int d = lane; d < Dc; d += 64) s += hrow[d] * wrow[d];
      for (int m = 1; m < 64; m <<= 1) s += __shfl_xor(s, m);
      if (lane == 0) hp[(size_t)bi * Dc + e] = s + bv;
    }
  } else {
    int i = ((bx - 3072) * 256 + t) * 8;
    int e = i >> 10, d = i & 1023;
    const float* p = W + (size_t)e * 2048 + 1024 + d;
    float4 f0 = *(const float4*)p;
    float4 f1 = *(const float4*)(p + 4);
    uint4 o;
    o.x = pack2(f0.x, f0.y);
    o.y = pack2(f0.z, f0.w);
    o.z = pack2(f1.x, f1.y);
    o.w = pack2(f1.z, f1.w);
    *(uint4*)(webf + i) = o;
  }
}

// ---- kernel 2: scores GEMM (bf16 MFMA) + tanh + v-dot, per-e-tile partials.
// Round-12 body (best measured): counted vmcnt(4) across raw barriers,
// T2 both-sides LDS swizzle, T5 setprio, worklist mapping g=bx&255 /
// et=bx>>8 (XCD affinity: all 8 e-tiles of a panel share bx%8).
__global__ __launch_bounds__(256) void k_scores(const unsigned short* __restrict__ Ae,
                                                const unsigned short* __restrict__ We,
                                                const float* __restrict__ hp,
                                                const float* __restrict__ v,
                                                const int* __restrict__ wl,
                                                float* __restrict__ pscores) {
  int g = blockIdx.x & 255;
  int et = blockIdx.x >> 8;
  if (g >= wl[0]) return;
  int pk = wl[1 + g];
  int b = pk >> 8, sblk = pk & 255;
  int s0 = sblk * 128;
  int m0 = b * Sc + s0;
  int e0 = et * 128;

  __shared__ unsigned short As0[128 * 32];
  __shared__ unsigned short As1[128 * 32];
  __shared__ unsigned short Bs0[128 * 32];
  __shared__ unsigned short Bs1[128 * 32];
  __shared__ float hp_s[128], v_s[128], sc_s[128];

  int t = threadIdx.x;
  int w = t >> 6, lane = t & 63;
  if (t < 128) {
    hp_s[t] = hp[(size_t)b * Dc + e0 + t];
    v_s[t] = v[e0 + t];
    sc_s[t] = 0.f;
  }
  // Drain prologue loads (and their LDS writes) so vmcnt counting is exact.
  asm volatile("s_waitcnt vmcnt(0) lgkmcnt(0)" ::: "memory");

  f32x4 acc[4][4] = {};
  int wr = w >> 1, wc = w & 1;

  // Staging source pre-swizzle: octet o=t>>3 covers row-pair o (rows 2o,2o+1);
  // slot q=t&7 holds global slot g8=q^(o&7): row 2o+(g8>>2), chunk g8&3.
  {
    int o = t >> 3, q = t & 7;
    int g8 = q ^ (o & 7);
    int srow = 2 * o + (g8 >> 2);
    int scol = (g8 & 3) * 8;
    Ae += (size_t)(m0 + srow) * Dc + scol;
    We += (size_t)(e0 + srow) * Dc + scol;
  }
  const unsigned short* ga0 = Ae;
  const unsigned short* gb0 = We;

  // Read-side swizzle (per-lane constants).
  int posw = (((lane & 1) << 2) + (lane >> 4)) ^ (((lane & 15) >> 1) & 7);
  int aoff = (wr * 32 + ((lane & 15) >> 1)) * 64 + posw * 8;
  int boff = (wc * 32 + ((lane & 15) >> 1)) * 64 + posw * 8;

  auto stage = [&](int k0, unsigned short* A, unsigned short* B) {
    gload16(ga0 + k0, A + w * 512);
    gload16(ga0 + k0 + 64 * Dc, A + 2048 + w * 512);
    gload16(gb0 + k0, B + w * 512);
    gload16(gb0 + k0 + 64 * Dc, B + 2048 + w * 512);
  };
  auto compute = [&](const unsigned short* A, const unsigned short* B) {
    bf16x8 af[4], bfr[4];
#pragma unroll
    for (int m = 0; m < 4; m++)
      af[m] = __builtin_bit_cast(bf16x8, *(const uint4*)(A + aoff + m * 512));
#pragma unroll
    for (int n = 0; n < 4; n++)
      bfr[n] = __builtin_bit_cast(bf16x8, *(const uint4*)(B + boff + n * 512));
    __builtin_amdgcn_s_setprio(1);
#pragma unroll
    for (int m = 0; m < 4; m++)
#pragma unroll
      for (int n = 0; n < 4; n++)
        acc[m][n] = __builtin_amdgcn_mfma_f32_16x16x32_bf16(af[m], bfr[n], acc[m][n], 0, 0, 0);
    __builtin_amdgcn_s_setprio(0);
  };

  stage(0, As0, Bs0);  // 4 outstanding

#pragma unroll 1
  for (int i2 = 0; i2 < 15; ++i2) {
    stage((2 * i2 + 1) * 32, As1, Bs1);                // 8 outstanding
    asm volatile("s_waitcnt vmcnt(4)" ::: "memory");   // even tile landed
    __builtin_amdgcn_sched_barrier(0);
    __builtin_amdgcn_s_barrier();
    __builtin_amdgcn_sched_barrier(0);
    compute(As0, Bs0);
    __builtin_amdgcn_sched_barrier(0);
    __builtin_amdgcn_s_barrier();
    stage((2 * i2 + 2) * 32, As0, Bs0);
    asm volatile("s_waitcnt vmcnt(4)" ::: "memory");
    __builtin_amdgcn_sched_barrier(0);
    __builtin_amdgcn_s_barrier();
    __builtin_amdgcn_sched_barrier(0);
    compute(As1, Bs1);
    __builtin_amdgcn_sched_barrier(0);
    __builtin_amdgcn_s_barrier();
  }
  // tail: tile 30 in As0/Bs0; stage 31, compute both.
  stage(31 * 32, As1, Bs1);
  asm volatile("s_waitcnt vmcnt(4)" ::: "memory");
  __builtin_amdgcn_sched_barrier(0);
  __builtin_amdgcn_s_barrier();
  __builtin_amdgcn_sched_barrier(0);
  compute(As0, Bs0);
  __builtin_amdgcn_sched_barrier(0);
  __builtin_amdgcn_s_barrier();
  asm volatile("s_waitcnt vmcnt(0)" ::: "memory");
  __builtin_amdgcn_sched_barrier(0);
  __builtin_amdgcn_s_barrier();
  __builtin_amdgcn_sched_barrier(0);
  compute(As1, Bs1);

  // epilogue: rowsum_e( v[e] * tanh(acc + hp[e]) )
  for (int m = 0; m < 4; m++) {
    float rs0 = 0.f, rs1 = 0.f, rs2 = 0.f, rs3 = 0.f;
    for (int n = 0; n < 4; n++) {
      int ec = wc * 64 + n * 16 + (lane & 15);
      float hpv = hp_s[ec], vv = v_s[ec];
      f32x4 a = acc[m][n];
      rs0 += vv * tanh_fast(a[0] + hpv);
      rs1 += vv * tanh_fast(a[1] + hpv);
      rs2 += vv * tanh_fast(a[2] + hpv);
      rs3 += vv * tanh_fast(a[3] + hpv);
    }
    for (int mask = 1; mask < 16; mask <<= 1) {
      rs0 += __shfl_xor(rs0, mask);
      rs1 += __shfl_xor(rs1, mask);
      rs2 += __shfl_xor(rs2, mask);
      rs3 += __shfl_xor(rs3, mask);
    }
    if ((lane & 15) == 0) {  // exactly 2 adders per row (wc=0,1): deterministic
      int rbase = wr * 64 + m * 16 + (lane >> 4) * 4;
      atomicAdd(&sc_s[rbase + 0], rs0);
      atomicAdd(&sc_s[rbase + 1], rs1);
      atomicAdd(&sc_s[rbase + 2], rs2);
      atomicAdd(&sc_s[rbase + 3], rs3);
    }
  }
  __syncthreads();
  if (t < 128) pscores[((size_t)et * Bc + b) * Sc + s0 + t] = sc_s[t];
}

// ---- kernel 3: masked softmax over S per batch; sums 8 e-tile partials
__global__ __launch_bounds__(256) void k_softmax(const float* __restrict__ pscores,
                                                 const int* __restrict__ lengths,
                                                 float* __restrict__ attn) {
  int b = blockIdx.x, t = threadIdx.x;
  int len = lengths[b];
  float vals[8];
  float mx = -INFINITY;
  for (int i = 0; i < 8; i++) {
    int s = t + i * 256;
    float sc = 0.f;
    for (int p = 0; p < 8; p++) sc += pscores[((size_t)p * Bc + b) * Sc + s];
    sc = (s < len) ? sc : -INFINITY;
    vals[i] = sc;
    mx = fmaxf(mx, sc);
  }
  for (int m = 1; m < 64; m <<= 1) mx = fmaxf(mx, __shfl_xor(mx, m));
  __shared__ float rmax[4], rsum[4];
  int w = t >> 6, lane = t & 63;
  if (lane == 0) rmax[w] = mx;
  __syncthreads();
  mx = fmaxf(fmaxf(rmax[0], rmax[1]), fmaxf(rmax[2], rmax[3]));
  float sm = 0.f;
  for (int i = 0; i < 8; i++) {
    vals[i] = __expf(vals[i] - mx);
    sm += vals[i];
  }
  for (int m = 1; m < 64; m <<= 1) sm += __shfl_xor(sm, m);
  if (lane == 0) rsum[w] = sm;
  __syncthreads();
  sm = rsum[0] + rsum[1] + rsum[2] + rsum[3];
  float inv = 1.f / sm;
  for (int i = 0; i < 8; i++) attn[(size_t)b * Sc + t + i * 256] = vals[i] * inv;
}

// ---- kernel 4: context partials from bf16 enc (half the traffic of fp32)
__global__ __launch_bounds__(256) void k_ctx(const unsigned short* __restrict__ ebf,
                                             const float* __restrict__ attn,
                                             const int* __restrict__ lengths,
                                             float* __restrict__ pctx) {
  int b = blockIdx.x >> 4, sp = blockIdx.x & 15;
  int t = threadIdx.x;
  int d0 = t * 4;
  int sbeg = sp * 128;
  float* outp = pctx + ((size_t)sp * Bc + b) * Dc + d0;
  int len = lengths[b];
  if (sbeg >= len) {
    *(float4*)outp = make_float4(0.f, 0.f, 0.f, 0.f);
    return;
  }
  __shared__ float at_s[128];
  if (t < 128) at_s[t] = attn[(size_t)b * Sc + sbeg + t];
  __syncthreads();
  float4 a = make_float4(0.f, 0.f, 0.f, 0.f);
  const unsigned short* ebase = ebf + ((size_t)b * Sc + sbeg) * Dc + d0;
  int ns = min(128, len - sbeg);
  for (int i = 0; i < ns; i++) {
    float wt = at_s[i];
    uint2 u = *(const uint2*)(ebase + (size_t)i * Dc);
    a.x += wt * __uint_as_float(u.x << 16);
    a.y += wt * __uint_as_float(u.x & 0xffff0000u);
    a.z += wt * __uint_as_float(u.y << 16);
    a.w += wt * __uint_as_float(u.y & 0xffff0000u);
  }
  *(float4*)outp = a;
}

// ---- kernel 5: reduce 16 context partials -> out (B,1,D)
__global__ __launch_bounds__(256) void k_reduce(const float* __restrict__ pctx,
                                               float* __restrict__ out) {
  int i = blockIdx.x * 256 + threadIdx.x;
  int b = i >> 10, d = i & 1023;
  float s = 0.f;
  for (int p = 0; p < 16; p++) s += pctx[((size_t)p * Bc + b) * Dc + d];
  out[i] = s;
}

extern "C" void kernel_launch(void* const* d_in, const int* in_sizes, int n_in,
                              void* d_out, int out_size, void* d_ws, size_t ws_size,
                              hipStream_t stream) {
  const float* enc = (const float*)d_in[0];
  const float* hidden = (const float*)d_in[1];
  const int* lengths = (const int*)d_in[2];
  const float* W = (const float*)d_in[3];
  const float* bias = (const float*)d_in[4];
  const float* v = (const float*)d_in[5];
  float* out = (float*)d_out;

  char* ws = (char*)d_ws;
  unsigned short* ebf = (unsigned short*)ws;                // 64 MB
  unsigned short* webf = (unsigned short*)(ws + 67108864);  // 2 MB
  float* hp = (float*)(ws + 69206016);                      // 64 KB
  float* pscores = (float*)(ws + 69271552);                 // 1 MB
  float* attn = (float*)(ws + 70320128);                    // 128 KB
  float* pctx = (float*)(ws + 70451200);                    // 1 MB
  int* wl = (int*)(ws + 71499776);                          // worklist

  hipLaunchKernelGGL(k_prep, dim3(3584), dim3(256), 0, stream, enc, hidden, W, bias,
                     lengths, ebf, webf, hp, wl);
  hipLaunchKernelGGL(k_scores, dim3(2048), dim3(256), 0, stream, ebf, webf, hp, v,
                     wl, pscores);
  hipLaunchKernelGGL(k_softmax, dim3(16), dim3(256), 0, stream, pscores, lengths, attn);
  hipLaunchKernelGGL(k_ctx, dim3(256), dim3(256), 0, stream, ebf, attn, lengths, pctx);
  hipLaunchKernelGGL(k_reduce, dim3(64), dim3(256), 0, stream, pctx, out);
}